// Round 11
// baseline (388.742 us; speedup 1.0000x reference)
//
#include <hip/hip_runtime.h>

#define NN 100000
#define NE 1600000
#define INF 128
#define HID 150
#define NOUT 128

// radix-by-bucket CSR build params (atomic build refuted r9: fill_csr 128us,
// WRITE_SIZE 108MB masked lines + per-cursor atomic serialization)
#define NBK 196        // buckets = ceil(NN/512); bucket(d) = d>>9
#define WGS 400        // sort workgroups
#define EPW 4000       // edges per sort workgroup (WGS*EPW == NE exactly)
#define CNTL (NBK * WGS)
#define CAP2 10240     // LDS span cap in buildcsr (mean 8192, +22 sigma)

typedef __attribute__((ext_vector_type(8))) short bf16x8;
typedef __attribute__((ext_vector_type(8))) unsigned short u16x8;
typedef __attribute__((ext_vector_type(4))) float f32x4;
typedef __attribute__((ext_vector_type(2))) float f32x2;

__device__ inline unsigned short f2bf(float f) {
    unsigned int u = __float_as_uint(f);
    u += 0x7fffu + ((u >> 16) & 1u);
    return (unsigned short)(u >> 16);
}
__device__ inline float bflo(unsigned int t) { return __uint_as_float(t << 16); }
__device__ inline float bfhi(unsigned int t) { return __uint_as_float(t & 0xffff0000u); }

// ---------------- radix sort by dst bucket ----------------

__global__ __launch_bounds__(256) void sort1(const int* __restrict__ src,
                                             const int* __restrict__ dst,
                                             unsigned int* __restrict__ chunkw,
                                             int* __restrict__ cntm) {
    __shared__ int hist[NBK];
    __shared__ int off[NBK];
    __shared__ int s[256];
    __shared__ unsigned int buf[EPW];
    int w = blockIdx.x, tid = threadIdx.x;
    int e0 = w * EPW;
    for (int i = tid; i < NBK; i += 256) hist[i] = 0;
    __syncthreads();
    for (int i = tid; i < EPW; i += 256) atomicAdd(&hist[dst[e0 + i] >> 9], 1);
    __syncthreads();
    int v = (tid < NBK) ? hist[tid] : 0;
    s[tid] = v;
    __syncthreads();
    for (int o = 1; o < 256; o <<= 1) {
        int t = (tid >= o) ? s[tid - o] : 0;
        __syncthreads();
        s[tid] += t;
        __syncthreads();
    }
    if (tid < NBK) {
        off[tid] = s[tid] - v;          // exclusive
        cntm[tid * WGS + w] = v;
    }
    __syncthreads();
    for (int i = tid; i < EPW; i += 256) {
        int d = dst[e0 + i];
        int b = d >> 9;
        int p = atomicAdd(&off[b], 1);
        buf[p] = (unsigned int)src[e0 + i] | ((unsigned int)(d & 511) << 17);
    }
    __syncthreads();
    for (int i = tid; i < EPW; i += 256) chunkw[e0 + i] = buf[i];
}

__global__ void scanA(const int* __restrict__ in, int* __restrict__ excl,
                      int* __restrict__ blk_sums, int L) {
    __shared__ int s[256];
    int i = blockIdx.x * 256 + threadIdx.x;
    int d = (i < L) ? in[i] : 0;
    s[threadIdx.x] = d;
    __syncthreads();
    for (int o = 1; o < 256; o <<= 1) {
        int t = (threadIdx.x >= o) ? s[threadIdx.x - o] : 0;
        __syncthreads();
        s[threadIdx.x] += t;
        __syncthreads();
    }
    int incl = s[threadIdx.x];
    if (i < L) excl[i] = incl - d;
    if (threadIdx.x == 255) blk_sums[blockIdx.x] = incl;
}

__global__ void scanB(int* __restrict__ blk_sums, int nb) {
    __shared__ int s[512];
    int t = threadIdx.x;
    int v = (t < nb) ? blk_sums[t] : 0;
    s[t] = v;
    __syncthreads();
    for (int o = 1; o < 512; o <<= 1) {
        int u = (t >= o) ? s[t - o] : 0;
        __syncthreads();
        s[t] += u;
        __syncthreads();
    }
    if (t < nb) blk_sums[t] = s[t] - v;  // exclusive
}

__global__ void scanC(int* __restrict__ excl, const int* __restrict__ blk_sums, int L) {
    int i = blockIdx.x * 256 + threadIdx.x;
    if (i < L) excl[i] += blk_sums[blockIdx.x];
}

__global__ __launch_bounds__(256) void sort3(const unsigned int* __restrict__ chunkw,
                                             const int* __restrict__ cntm,
                                             const int* __restrict__ offm,
                                             unsigned int* __restrict__ bmaj) {
    __shared__ int excl[NBK + 1];
    __shared__ int dbase[NBK];
    __shared__ int s[256];
    int w = blockIdx.x, tid = threadIdx.x;
    int v = (tid < NBK) ? cntm[tid * WGS + w] : 0;
    if (tid < NBK) dbase[tid] = offm[tid * WGS + w];
    s[tid] = v;
    __syncthreads();
    for (int o = 1; o < 256; o <<= 1) {
        int t = (tid >= o) ? s[tid - o] : 0;
        __syncthreads();
        s[tid] += t;
        __syncthreads();
    }
    if (tid < NBK) excl[tid] = s[tid] - v;
    if (tid == 0) excl[NBK] = EPW;
    __syncthreads();
    int e0 = w * EPW;
    for (int i = tid; i < EPW; i += 256) {
        int lo = 0, hi = NBK;
        while (hi - lo > 1) {
            int mid = (lo + hi) >> 1;
            if (excl[mid] <= i) lo = mid; else hi = mid;
        }
        bmaj[dbase[lo] + (i - excl[lo])] = chunkw[e0 + i];
    }
}

__global__ __launch_bounds__(256) void buildcsr(const unsigned int* __restrict__ bmaj,
                                                const int* __restrict__ offm,
                                                int* __restrict__ csr_ptr,
                                                float* __restrict__ deg_inv,
                                                int* __restrict__ csr_src) {
    __shared__ int cnt[512];
    __shared__ int excl[512];
    __shared__ int off[512];
    __shared__ int s[256];
    __shared__ int span[CAP2];
    int b = blockIdx.x, tid = threadIdx.x;
    int base = offm[b * WGS];
    int nxt = (b == NBK - 1) ? NE : offm[(b + 1) * WGS];
    int n = nxt - base;
    if (n > CAP2) n = CAP2;  // memory-safety clamp (never hit for this input)
    for (int i = tid; i < 512; i += 256) cnt[i] = 0;
    __syncthreads();
    for (int i = tid; i < n; i += 256) atomicAdd(&cnt[bmaj[base + i] >> 17], 1);
    __syncthreads();
    int a0 = cnt[2 * tid], a1 = cnt[2 * tid + 1];
    int ps = a0 + a1;
    s[tid] = ps;
    __syncthreads();
    for (int o = 1; o < 256; o <<= 1) {
        int t = (tid >= o) ? s[tid - o] : 0;
        __syncthreads();
        s[tid] += t;
        __syncthreads();
    }
    int ex = s[tid] - ps;
    excl[2 * tid] = ex;
    excl[2 * tid + 1] = ex + a0;
    off[2 * tid] = ex;
    off[2 * tid + 1] = ex + a0;
    __syncthreads();
    for (int l = tid; l < 512; l += 256) {
        int g = b * 512 + l;
        if (g < NN) {
            csr_ptr[g] = base + excl[l];
            int d = cnt[l];
            deg_inv[g] = d > 0 ? 1.0f / (float)d : 0.0f;
        }
    }
    if (b == NBK - 1 && tid == 0) csr_ptr[NN] = NE;
    for (int i = tid; i < n; i += 256) {
        unsigned int wd = bmaj[base + i];
        int l = wd >> 17;
        int p = atomicAdd(&off[l], 1);
        span[p] = (int)(wd & 0x1FFFFu);
    }
    __syncthreads();
    for (int i = tid; i < n; i += 256) csr_src[base + i] = span[i];
}

// ---------------- casts / packing ----------------

__global__ void cast_bf16(const float* __restrict__ in, unsigned short* __restrict__ outb,
                          int n8) {
    int i = blockIdx.x * 256 + threadIdx.x;
    if (i >= n8) return;
    const f32x4* p = (const f32x4*)in;
    // x is read exactly once -> non-temporal to avoid polluting L2/L3
    f32x4 v0 = __builtin_nontemporal_load(&p[(size_t)i * 2]);
    f32x4 v1 = __builtin_nontemporal_load(&p[(size_t)i * 2 + 1]);
    u16x8 o = {f2bf(v0[0]), f2bf(v0[1]), f2bf(v0[2]), f2bf(v0[3]),
               f2bf(v1[0]), f2bf(v1[1]), f2bf(v1[2]), f2bf(v1[3])};
    ((u16x8*)outb)[i] = o;
}

__global__ void pack_weights(const float* __restrict__ Ws1, const float* __restrict__ Wn1,
                             const float* __restrict__ b1,
                             const float* __restrict__ Ws2, const float* __restrict__ Wn2,
                             unsigned short* __restrict__ W1t, unsigned short* __restrict__ W2t,
                             float* __restrict__ b1p) {
    int id = blockIdx.x * 256 + threadIdx.x;
    if (id < 160 * 256) {
        int n = id >> 8, k = id & 255;
        float v = 0.f;
        if (n < HID) v = (k < 128) ? Ws1[k * HID + n] : Wn1[(k - 128) * HID + n];
        W1t[id] = f2bf(v);
    } else if (id < 160 * 256 + 256 * 160) {
        int id2 = id - 160 * 256;
        int n = id2 / 160, k = id2 - n * 160;
        float v = 0.f;
        if (k < HID) v = (n < 128) ? Ws2[k * 128 + n] : Wn2[k * 128 + (n - 128)];
        W2t[id2] = f2bf(v);
    } else if (id < 160 * 256 + 256 * 160 + 160) {
        int n = id - (160 * 256 + 256 * 160);
        b1p[n] = (n < HID) ? b1[n] : 0.f;
    }
}

// ---------------- aggregation: quad-edge dwordx4 gather ----------------
// Gather at structural roofline: FETCH ~= 8 XCD x table size, ~3.8 TB/s
// (r4/r6: VALU/MLP changes flat). Wave layout: rg = lane>>4 (4 edges),
// ch = lane&15 (16B chunk); shfl_xor(32,16) merges; lanes 0..15 hold the row.

#define AGG_ACC(t)                              \
    accA += (f32x2){bflo(t.x), bfhi(t.x)};      \
    accB += (f32x2){bflo(t.y), bfhi(t.y)};      \
    accC += (f32x2){bflo(t.z), bfhi(t.z)};      \
    accD += (f32x2){bflo(t.w), bfhi(t.w)};

#define AGG_BODY(FTBL)                                                 \
    int e = start;                                                     \
    for (; e + 16 <= end; e += 16) {                                   \
        int s0 = csr_src[e + rg];                                      \
        int s1 = csr_src[e + 4 + rg];                                  \
        int s2 = csr_src[e + 8 + rg];                                  \
        int s3 = csr_src[e + 12 + rg];                                 \
        uint4 t0 = FTBL[(size_t)s0 * 16 + ch];                         \
        uint4 t1 = FTBL[(size_t)s1 * 16 + ch];                         \
        uint4 t2 = FTBL[(size_t)s2 * 16 + ch];                         \
        uint4 t3 = FTBL[(size_t)s3 * 16 + ch];                         \
        AGG_ACC(t0);                                                   \
        AGG_ACC(t1);                                                   \
        AGG_ACC(t2);                                                   \
        AGG_ACC(t3);                                                   \
    }                                                                  \
    if (e + 8 <= end) {                                                \
        int s0 = csr_src[e + rg];                                      \
        int s1 = csr_src[e + 4 + rg];                                  \
        uint4 t0 = FTBL[(size_t)s0 * 16 + ch];                         \
        uint4 t1 = FTBL[(size_t)s1 * 16 + ch];                         \
        AGG_ACC(t0);                                                   \
        AGG_ACC(t1);                                                   \
        e += 8;                                                        \
    }                                                                  \
    if (e + 4 <= end) {                                                \
        int s0 = csr_src[e + rg];                                      \
        uint4 t0 = FTBL[(size_t)s0 * 16 + ch];                         \
        AGG_ACC(t0);                                                   \
        e += 4;                                                        \
    }                                                                  \
    int rem = end - e;                                                 \
    if (rem > 0) {                                                     \
        int s0 = csr_src[(rg < rem) ? (e + rg) : e];                   \
        uint4 t = FTBL[(size_t)s0 * 16 + ch];                          \
        float wt = (rg < rem) ? 1.f : 0.f;                             \
        f32x2 w2 = {wt, wt};                                           \
        accA += w2 * (f32x2){bflo(t.x), bfhi(t.x)};                    \
        accB += w2 * (f32x2){bflo(t.y), bfhi(t.y)};                    \
        accC += w2 * (f32x2){bflo(t.z), bfhi(t.z)};                    \
        accD += w2 * (f32x2){bflo(t.w), bfhi(t.w)};                    \
    }                                                                  \
    float acc0 = accA[0], acc1 = accA[1];                              \
    float acc2 = accB[0], acc3 = accB[1];                              \
    float acc4 = accC[0], acc5 = accC[1];                              \
    float acc6 = accD[0], acc7 = accD[1];                              \
    acc0 += __shfl_xor(acc0, 32); acc1 += __shfl_xor(acc1, 32);        \
    acc2 += __shfl_xor(acc2, 32); acc3 += __shfl_xor(acc3, 32);        \
    acc4 += __shfl_xor(acc4, 32); acc5 += __shfl_xor(acc5, 32);        \
    acc6 += __shfl_xor(acc6, 32); acc7 += __shfl_xor(acc7, 32);        \
    acc0 += __shfl_xor(acc0, 16); acc1 += __shfl_xor(acc1, 16);        \
    acc2 += __shfl_xor(acc2, 16); acc3 += __shfl_xor(acc3, 16);        \
    acc4 += __shfl_xor(acc4, 16); acc5 += __shfl_xor(acc5, 16);        \
    acc6 += __shfl_xor(acc6, 16); acc7 += __shfl_xor(acc7, 16);

__global__ __launch_bounds__(256) void agg_add_q(
    const unsigned short* __restrict__ zb, const int* __restrict__ csr_ptr,
    const float* __restrict__ deg_inv, const int* __restrict__ csr_src,
    float* __restrict__ out) {
    int wid = threadIdx.x >> 6;
    int lane = threadIdx.x & 63;
    int v = blockIdx.x * 4 + wid;
    int start = csr_ptr[v], end = csr_ptr[v + 1];
    int rg = lane >> 4, ch = lane & 15;
    const uint4* f4 = (const uint4*)zb;
    f32x2 accA = {0.f, 0.f}, accB = {0.f, 0.f};
    f32x2 accC = {0.f, 0.f}, accD = {0.f, 0.f};
    AGG_BODY(f4);
    if (lane < 16) {
        float di = deg_inv[v];
        f32x4* o4 = (f32x4*)out;  // 32 f32x4 per 512B row
        size_t base = (size_t)v * 32 + ch * 2;
        f32x4 c0 = __builtin_nontemporal_load(&o4[base]);
        f32x4 c1 = __builtin_nontemporal_load(&o4[base + 1]);
        c0[0] += acc0 * di; c0[1] += acc1 * di; c0[2] += acc2 * di; c0[3] += acc3 * di;
        c1[0] += acc4 * di; c1[1] += acc5 * di; c1[2] += acc6 * di; c1[3] += acc7 * di;
        __builtin_nontemporal_store(c0, &o4[base]);
        __builtin_nontemporal_store(c1, &o4[base + 1]);
    }
}

// ---------------- fused layer-1: aggregate-into-LDS + MFMA GEMM ----------------
// Per block (64 nodes): phase 1 gathers+means the block's 64 agg rows into LDS
// (no global aggb roundtrip, no cross-block dependency); phase 2 runs the
// M=64 GEMM with A cols 0-127 from xb, cols 128-255 from the LDS agg tile.
// Latency-bound phases overlap ACROSS resident blocks (4/CU at 35KB LDS).

__global__ __launch_bounds__(256, 4) void fused1(
    const unsigned short* __restrict__ xb, const int* __restrict__ csr_ptr,
    const float* __restrict__ deg_inv, const int* __restrict__ csr_src,
    const unsigned short* __restrict__ W1t, const float* __restrict__ b1p,
    unsigned short* __restrict__ h1b) {
    __shared__ __align__(16) unsigned short A_lds[64][40];
    __shared__ __align__(16) unsigned short B_lds[160][40];
    __shared__ __align__(16) unsigned short A2[64][136];  // agg rows, bf16
    int tid = threadIdx.x;
    int m0 = blockIdx.x * 64;
    int w = tid >> 6, lane = tid & 63;

    // ---- phase 1: wave w aggregates nodes m0 + w*16 .. +15 ----
    {
        int rg = lane >> 4, ch = lane & 15;
        const uint4* f4 = (const uint4*)xb;
        #pragma unroll 1
        for (int i = 0; i < 16; i++) {
            int v = m0 + w * 16 + i;
            f32x2 accA = {0.f, 0.f}, accB = {0.f, 0.f};
            f32x2 accC = {0.f, 0.f}, accD = {0.f, 0.f};
            int start = 0, end = 0;
            if (v < NN) { start = csr_ptr[v]; end = csr_ptr[v + 1]; }
            AGG_BODY(f4);
            if (lane < 16) {
                float di = (v < NN) ? deg_inv[v] : 0.f;
                u16x8 o = {f2bf(acc0 * di), f2bf(acc1 * di), f2bf(acc2 * di), f2bf(acc3 * di),
                           f2bf(acc4 * di), f2bf(acc5 * di), f2bf(acc6 * di), f2bf(acc7 * di)};
                *(u16x8*)&A2[w * 16 + i][ch * 8] = o;
            }
        }
    }
    __syncthreads();

    // ---- phase 2: M=64 GEMM over K=256 (128 self + 128 agg) ----
    int lrow = lane & 15, quad = lane >> 4;
    int wr = (w & 1) * 32;
    int wc = (w >> 1) * 80;
    f32x4 acc[2][5];
    #pragma unroll
    for (int r = 0; r < 2; r++)
        #pragma unroll
        for (int c = 0; c < 5; c++) acc[r][c] = (f32x4){0.f, 0.f, 0.f, 0.f};

    for (int k0 = 0; k0 < 256; k0 += 32) {
        __syncthreads();
        {
            int row = tid >> 2, ch = tid & 3;
            u16x8 val = {0, 0, 0, 0, 0, 0, 0, 0};
            if (k0 < 128) {
                int gm = m0 + row, gk = k0 + ch * 8;
                if (gm < NN) val = *(const u16x8*)(xb + (size_t)gm * 128 + gk);
            } else {
                val = *(const u16x8*)&A2[row][(k0 - 128) + ch * 8];
            }
            *(u16x8*)&A_lds[row][ch * 8] = val;
        }
        #pragma unroll
        for (int i = 0; i < 3; i++) {
            int idx = tid + i * 256;
            if (idx < 640) {
                int n = idx >> 2, ch = idx & 3;
                u16x8 val = *(const u16x8*)(W1t + (size_t)n * 256 + k0 + ch * 8);
                *(u16x8*)&B_lds[n][ch * 8] = val;
            }
        }
        __syncthreads();
        bf16x8 a[2], b[5];
        #pragma unroll
        for (int r = 0; r < 2; r++)
            a[r] = *(const bf16x8*)&A_lds[wr + r * 16 + lrow][quad * 8];
        #pragma unroll
        for (int c = 0; c < 5; c++)
            b[c] = *(const bf16x8*)&B_lds[wc + c * 16 + lrow][quad * 8];
        #pragma unroll
        for (int r = 0; r < 2; r++)
            #pragma unroll
            for (int c = 0; c < 5; c++)
                acc[r][c] = __builtin_amdgcn_mfma_f32_16x16x32_bf16(a[r], b[c], acc[r][c], 0, 0, 0);
    }
    #pragma unroll
    for (int r = 0; r < 2; r++) {
        #pragma unroll
        for (int rr = 0; rr < 4; rr++) {
            int gm = m0 + wr + r * 16 + quad * 4 + rr;
            if (gm < NN) {
                #pragma unroll
                for (int c = 0; c < 5; c++) {
                    int gn = wc + c * 16 + lrow;
                    float val = acc[r][c][rr] + b1p[gn];
                    val = val > 0.f ? val : 0.f;
                    h1b[(size_t)gm * 160 + gn] = f2bf(val);
                }
            }
        }
    }
}

// ---------------- gemm2 (M=64 tile, latency-optimized r10) ----------------

__global__ __launch_bounds__(256, 4) void gemm2_mfma(
    const unsigned short* __restrict__ h1b, const unsigned short* __restrict__ W2t,
    const float* __restrict__ b2, float* __restrict__ out,
    unsigned short* __restrict__ zb) {
    __shared__ __align__(16) unsigned short A_lds[64][40];
    __shared__ __align__(16) unsigned short B_lds[128][40];
    int tid = threadIdx.x;
    int m0 = blockIdx.x * 64;
    int n0 = blockIdx.y * 128;
    int w = tid >> 6, lane = tid & 63;
    int lrow = lane & 15, quad = lane >> 4;
    int wr = (w & 1) * 32;
    int wc = (w >> 1) * 64;
    f32x4 acc[2][4];
    #pragma unroll
    for (int r = 0; r < 2; r++)
        #pragma unroll
        for (int c = 0; c < 4; c++) acc[r][c] = (f32x4){0.f, 0.f, 0.f, 0.f};

    for (int k0 = 0; k0 < 160; k0 += 32) {
        __syncthreads();
        {
            int row = tid >> 2, ch = tid & 3;
            int gm = m0 + row;
            u16x8 val = {0, 0, 0, 0, 0, 0, 0, 0};
            if (gm < NN) val = *(const u16x8*)(h1b + (size_t)gm * 160 + k0 + ch * 8);
            *(u16x8*)&A_lds[row][ch * 8] = val;
        }
        #pragma unroll
        for (int i = 0; i < 2; i++) {
            int idx = tid + i * 256;
            int n = idx >> 2, ch = idx & 3;
            u16x8 val = *(const u16x8*)(W2t + (size_t)(n0 + n) * 160 + k0 + ch * 8);
            *(u16x8*)&B_lds[n][ch * 8] = val;
        }
        __syncthreads();
        bf16x8 a[2], b[4];
        #pragma unroll
        for (int r = 0; r < 2; r++)
            a[r] = *(const bf16x8*)&A_lds[wr + r * 16 + lrow][quad * 8];
        #pragma unroll
        for (int c = 0; c < 4; c++)
            b[c] = *(const bf16x8*)&B_lds[wc + c * 16 + lrow][quad * 8];
        #pragma unroll
        for (int r = 0; r < 2; r++)
            #pragma unroll
            for (int c = 0; c < 4; c++)
                acc[r][c] = __builtin_amdgcn_mfma_f32_16x16x32_bf16(a[r], b[c], acc[r][c], 0, 0, 0);
    }
    #pragma unroll
    for (int r = 0; r < 2; r++) {
        #pragma unroll
        for (int rr = 0; rr < 4; rr++) {
            int gm = m0 + wr + r * 16 + quad * 4 + rr;
            if (gm < NN) {
                #pragma unroll
                for (int c = 0; c < 4; c++) {
                    int gn = wc + c * 16 + lrow;
                    float val = acc[r][c][rr];
                    if (n0 == 0) {
                        out[(size_t)gm * 128 + gn] = val + b2[gn];
                    } else {
                        zb[(size_t)gm * 128 + gn] = f2bf(val);
                    }
                }
            }
        }
    }
}

// ---------------- launch ----------------

extern "C" void kernel_launch(void* const* d_in, const int* in_sizes, int n_in,
                              void* d_out, int out_size, void* d_ws, size_t ws_size,
                              hipStream_t stream) {
    const float* x   = (const float*)d_in[0];
    const int* src   = (const int*)d_in[1];
    const int* dst   = (const int*)d_in[2];
    const float* Ws1 = (const float*)d_in[3];
    const float* Wn1 = (const float*)d_in[4];
    const float* b1  = (const float*)d_in[5];
    const float* Ws2 = (const float*)d_in[6];
    const float* Wn2 = (const float*)d_in[7];
    const float* b2  = (const float*)d_in[8];
    float* out = (float*)d_out;

    char* p = (char*)d_ws;
    auto carve = [&](size_t bytes) {
        void* r = (void*)p;
        p += (bytes + 255) & ~(size_t)255;
        return r;
    };
    int*   csr_ptr  = (int*)carve((size_t)(NN + 1) * 4);
    float* deg_inv  = (float*)carve((size_t)NN * 4);
    int*   csr_src  = (int*)carve((size_t)NE * 4);
    int*   cntm     = (int*)carve((size_t)CNTL * 4);
    int*   offm     = (int*)carve((size_t)CNTL * 4);
    int*   blk2     = (int*)carve(512 * 4);
    unsigned short* xb   = (unsigned short*)carve((size_t)NN * 128 * 2);
    unsigned short* zb   = (unsigned short*)carve((size_t)NN * 128 * 2);
    unsigned short* W1t  = (unsigned short*)carve(160 * 256 * 2);
    unsigned short* W2t  = (unsigned short*)carve(256 * 160 * 2);
    float* b1p           = (float*)carve(160 * 4);
    unsigned short* h1b  = (unsigned short*)carve((size_t)NN * 160 * 2);
    // sort buffers alias h1b's 32 MB region (dead until fused1 runs)
    unsigned int* chunkw = (unsigned int*)h1b;                            // 6.4 MB
    unsigned int* bmaj   = (unsigned int*)((char*)h1b + (size_t)NE * 4);  // 6.4 MB

    // CSR build: radix sort by bucket, no global atomics (~30us total; the
    // atomic-fill alternative was 128us in fill_csr alone — r9)
    sort1<<<WGS, 256, 0, stream>>>(src, dst, chunkw, cntm);
    const int SB = (CNTL + 255) / 256;  // 307
    scanA<<<SB, 256, 0, stream>>>(cntm, offm, blk2, CNTL);
    scanB<<<1, 512, 0, stream>>>(blk2, SB);
    scanC<<<SB, 256, 0, stream>>>(offm, blk2, CNTL);
    sort3<<<WGS, 256, 0, stream>>>(chunkw, cntm, offm, bmaj);
    buildcsr<<<NBK, 256, 0, stream>>>(bmaj, offm, csr_ptr, deg_inv, csr_src);

    // casts + weight packing
    cast_bf16<<<(NN * 128 / 8 + 255) / 256, 256, 0, stream>>>(x, xb, NN * 128 / 8);
    pack_weights<<<(160 * 256 + 256 * 160 + 160 + 255) / 256, 256, 0, stream>>>(
        Ws1, Wn1, b1, Ws2, Wn2, W1t, W2t, b1p);

    // layer 1 (fused aggregate + GEMM)
    fused1<<<dim3((NN + 63) / 64, 1), 256, 0, stream>>>(
        xb, csr_ptr, deg_inv, csr_src, W1t, b1p, h1b);

    // layer 2
    gemm2_mfma<<<dim3((NN + 63) / 64, 2), 256, 0, stream>>>(h1b, W2t, b2, out, zb);
    agg_add_q<<<NN / 4, 256, 0, stream>>>(zb, csr_ptr, deg_inv, csr_src, out);

    (void)in_sizes; (void)n_in; (void)out_size; (void)ws_size;
}

// Round 13
// 354.418 us; speedup vs baseline: 1.0968x; 1.0968x over previous
//
#include <hip/hip_runtime.h>

#define NN 100000
#define NE 1600000
#define INF 128
#define HID 150
#define NOUT 128

// radix-by-bucket CSR build params (atomic build refuted r9: fill_csr 128us;
// fused agg+gemm refuted r11: LDS-capped occupancy halves gather BW)
#define NBK 196        // buckets = ceil(NN/512); bucket(d) = d>>9
#define WGS 400        // sort workgroups
#define EPW 4000       // edges per sort workgroup (WGS*EPW == NE exactly)
#define CNTL (NBK * WGS)
#define CAP2 10240     // LDS span cap in buildcsr2 (mean 8192, +22 sigma)

typedef __attribute__((ext_vector_type(8))) short bf16x8;
typedef __attribute__((ext_vector_type(8))) unsigned short u16x8;
typedef __attribute__((ext_vector_type(4))) float f32x4;
typedef __attribute__((ext_vector_type(2))) float f32x2;

__device__ inline unsigned short f2bf(float f) {
    unsigned int u = __float_as_uint(f);
    u += 0x7fffu + ((u >> 16) & 1u);
    return (unsigned short)(u >> 16);
}
__device__ inline float bflo(unsigned int t) { return __uint_as_float(t << 16); }
__device__ inline float bfhi(unsigned int t) { return __uint_as_float(t & 0xffff0000u); }

// ---------------- radix sort by dst bucket ----------------

__global__ __launch_bounds__(256) void sort1(const int* __restrict__ src,
                                             const int* __restrict__ dst,
                                             unsigned int* __restrict__ chunkw,
                                             int* __restrict__ cntm,
                                             int* __restrict__ segsta) {
    __shared__ int hist[NBK];
    __shared__ int off[NBK];
    __shared__ int s[256];
    __shared__ unsigned int buf[EPW];
    int w = blockIdx.x, tid = threadIdx.x;
    int e0 = w * EPW;
    for (int i = tid; i < NBK; i += 256) hist[i] = 0;
    __syncthreads();
    for (int i = tid; i < EPW; i += 256) atomicAdd(&hist[dst[e0 + i] >> 9], 1);
    __syncthreads();
    int v = (tid < NBK) ? hist[tid] : 0;
    s[tid] = v;
    __syncthreads();
    for (int o = 1; o < 256; o <<= 1) {
        int t = (tid >= o) ? s[tid - o] : 0;
        __syncthreads();
        s[tid] += t;
        __syncthreads();
    }
    if (tid < NBK) {
        int ex = s[tid] - v;            // exclusive within this workgroup
        off[tid] = ex;
        cntm[tid * WGS + w] = v;
        segsta[tid * WGS + w] = ex;     // bucket tid's segment start in chunk w
    }
    __syncthreads();
    for (int i = tid; i < EPW; i += 256) {
        int d = dst[e0 + i];
        int b = d >> 9;
        int p = atomicAdd(&off[b], 1);
        buf[p] = (unsigned int)src[e0 + i] | ((unsigned int)(d & 511) << 17);
    }
    __syncthreads();
    for (int i = tid; i < EPW; i += 256) chunkw[e0 + i] = buf[i];
}

__global__ void scanA(const int* __restrict__ in, int* __restrict__ excl,
                      int* __restrict__ blk_sums, int L) {
    __shared__ int s[256];
    int i = blockIdx.x * 256 + threadIdx.x;
    int d = (i < L) ? in[i] : 0;
    s[threadIdx.x] = d;
    __syncthreads();
    for (int o = 1; o < 256; o <<= 1) {
        int t = (threadIdx.x >= o) ? s[threadIdx.x - o] : 0;
        __syncthreads();
        s[threadIdx.x] += t;
        __syncthreads();
    }
    int incl = s[threadIdx.x];
    if (i < L) excl[i] = incl - d;
    if (threadIdx.x == 255) blk_sums[blockIdx.x] = incl;
}

__global__ void scanB(int* __restrict__ blk_sums, int nb) {
    __shared__ int s[512];
    int t = threadIdx.x;
    int v = (t < nb) ? blk_sums[t] : 0;
    s[t] = v;
    __syncthreads();
    for (int o = 1; o < 512; o <<= 1) {
        int u = (t >= o) ? s[t - o] : 0;
        __syncthreads();
        s[t] += u;
        __syncthreads();
    }
    if (t < nb) blk_sums[t] = s[t] - v;  // exclusive
}

__global__ void scanC(int* __restrict__ excl, const int* __restrict__ blk_sums, int L) {
    int i = blockIdx.x * 256 + threadIdx.x;
    if (i < L) excl[i] += blk_sums[blockIdx.x];
}

// merged sort3+buildcsr: reads bucket-b edges directly from the 400
// per-workgroup segments of chunkw (located by segsta/cntm). The LDS span
// scatter is atomicAdd-based, so bucket-major ordering (old bmaj) was never
// needed — saves 12.8MB bmaj traffic, 3.2M binary-search steps, one launch.
__global__ __launch_bounds__(256) void buildcsr2(const unsigned int* __restrict__ chunkw,
                                                 const int* __restrict__ cntm,
                                                 const int* __restrict__ segsta,
                                                 const int* __restrict__ offm,
                                                 int* __restrict__ csr_ptr,
                                                 float* __restrict__ deg_inv,
                                                 int* __restrict__ csr_src) {
    __shared__ int cnt[512];
    __shared__ int excl[512];
    __shared__ int off[512];
    __shared__ int s[256];
    __shared__ int span[CAP2];
    int b = blockIdx.x, tid = threadIdx.x;
    int base = offm[b * WGS];
    int nxt = (b == NBK - 1) ? NE : offm[(b + 1) * WGS];
    int n = nxt - base;
    if (n > CAP2) n = CAP2;  // memory-safety clamp (never hit for this input)
    for (int i = tid; i < 512; i += 256) cnt[i] = 0;
    __syncthreads();
    // count pass over this bucket's segments
    for (int sg = tid; sg < WGS; sg += 256) {
        int c = cntm[b * WGS + sg];
        int st = sg * EPW + segsta[b * WGS + sg];
        for (int j = 0; j < c; j++) atomicAdd(&cnt[chunkw[st + j] >> 17], 1);
    }
    __syncthreads();
    int a0 = cnt[2 * tid], a1 = cnt[2 * tid + 1];
    int ps = a0 + a1;
    s[tid] = ps;
    __syncthreads();
    for (int o = 1; o < 256; o <<= 1) {
        int t = (tid >= o) ? s[tid - o] : 0;
        __syncthreads();
        s[tid] += t;
        __syncthreads();
    }
    int ex = s[tid] - ps;
    excl[2 * tid] = ex;
    excl[2 * tid + 1] = ex + a0;
    off[2 * tid] = ex;
    off[2 * tid + 1] = ex + a0;
    __syncthreads();
    for (int l = tid; l < 512; l += 256) {
        int g = b * 512 + l;
        if (g < NN) {
            csr_ptr[g] = base + excl[l];
            int d = cnt[l];
            deg_inv[g] = d > 0 ? 1.0f / (float)d : 0.0f;
        }
    }
    if (b == NBK - 1 && tid == 0) csr_ptr[NN] = NE;
    // scatter pass
    for (int sg = tid; sg < WGS; sg += 256) {
        int c = cntm[b * WGS + sg];
        int st = sg * EPW + segsta[b * WGS + sg];
        for (int j = 0; j < c; j++) {
            unsigned int wd = chunkw[st + j];
            int l = wd >> 17;
            int p = atomicAdd(&off[l], 1);
            if (p < CAP2) span[p] = (int)(wd & 0x1FFFFu);
        }
    }
    __syncthreads();
    for (int i = tid; i < n; i += 256) csr_src[base + i] = span[i];
}

// ---------------- casts / packing ----------------

__global__ void cast_bf16(const float* __restrict__ in, unsigned short* __restrict__ outb,
                          int n8) {
    int i = blockIdx.x * 256 + threadIdx.x;
    if (i >= n8) return;
    const f32x4* p = (const f32x4*)in;
    // x is read exactly once -> non-temporal to avoid polluting L2/L3
    f32x4 v0 = __builtin_nontemporal_load(&p[(size_t)i * 2]);
    f32x4 v1 = __builtin_nontemporal_load(&p[(size_t)i * 2 + 1]);
    u16x8 o = {f2bf(v0[0]), f2bf(v0[1]), f2bf(v0[2]), f2bf(v0[3]),
               f2bf(v1[0]), f2bf(v1[1]), f2bf(v1[2]), f2bf(v1[3])};
    ((u16x8*)outb)[i] = o;
}

__global__ void pack_weights(const float* __restrict__ Ws1, const float* __restrict__ Wn1,
                             const float* __restrict__ b1,
                             const float* __restrict__ Ws2, const float* __restrict__ Wn2,
                             unsigned short* __restrict__ W1t, unsigned short* __restrict__ W2t,
                             float* __restrict__ b1p) {
    int id = blockIdx.x * 256 + threadIdx.x;
    if (id < 160 * 256) {
        int n = id >> 8, k = id & 255;
        float v = 0.f;
        if (n < HID) v = (k < 128) ? Ws1[k * HID + n] : Wn1[(k - 128) * HID + n];
        W1t[id] = f2bf(v);
    } else if (id < 160 * 256 + 256 * 160) {
        int id2 = id - 160 * 256;
        int n = id2 / 160, k = id2 - n * 160;
        float v = 0.f;
        if (k < HID) v = (n < 128) ? Ws2[k * 128 + n] : Wn2[k * 128 + (n - 128)];
        W2t[id2] = f2bf(v);
    } else if (id < 160 * 256 + 256 * 160 + 160) {
        int n = id - (160 * 256 + 256 * 160);
        b1p[n] = (n < HID) ? b1[n] : 0.f;
    }
}

// ---------------- aggregation: quad-edge dwordx4 gather ----------------
// At structural roofline: FETCH ~= 8 XCD x table size (random gather, per-XCD
// L2 streams the whole table), ~3.8 TB/s at ~72% occupancy. Occupancy is the
// binding resource (r11: fused version at 32% occ -> 1.97 TB/s). Wave layout:
// rg = lane>>4 (4 edges), ch = lane&15 (16B chunk); shfl_xor(32,16) merges.

#define AGG_ACC(t)                              \
    accA += (f32x2){bflo(t.x), bfhi(t.x)};      \
    accB += (f32x2){bflo(t.y), bfhi(t.y)};      \
    accC += (f32x2){bflo(t.z), bfhi(t.z)};      \
    accD += (f32x2){bflo(t.w), bfhi(t.w)};

#define AGG_BODY(FTBL)                                                 \
    int e = start;                                                     \
    for (; e + 16 <= end; e += 16) {                                   \
        int s0 = csr_src[e + rg];                                      \
        int s1 = csr_src[e + 4 + rg];                                  \
        int s2 = csr_src[e + 8 + rg];                                  \
        int s3 = csr_src[e + 12 + rg];                                 \
        uint4 t0 = FTBL[(size_t)s0 * 16 + ch];                         \
        uint4 t1 = FTBL[(size_t)s1 * 16 + ch];                         \
        uint4 t2 = FTBL[(size_t)s2 * 16 + ch];                         \
        uint4 t3 = FTBL[(size_t)s3 * 16 + ch];                         \
        AGG_ACC(t0);                                                   \
        AGG_ACC(t1);                                                   \
        AGG_ACC(t2);                                                   \
        AGG_ACC(t3);                                                   \
    }                                                                  \
    if (e + 8 <= end) {                                                \
        int s0 = csr_src[e + rg];                                      \
        int s1 = csr_src[e + 4 + rg];                                  \
        uint4 t0 = FTBL[(size_t)s0 * 16 + ch];                         \
        uint4 t1 = FTBL[(size_t)s1 * 16 + ch];                         \
        AGG_ACC(t0);                                                   \
        AGG_ACC(t1);                                                   \
        e += 8;                                                        \
    }                                                                  \
    if (e + 4 <= end) {                                                \
        int s0 = csr_src[e + rg];                                      \
        uint4 t0 = FTBL[(size_t)s0 * 16 + ch];                         \
        AGG_ACC(t0);                                                   \
        e += 4;                                                        \
    }                                                                  \
    int rem = end - e;                                                 \
    if (rem > 0) {                                                     \
        int s0 = csr_src[(rg < rem) ? (e + rg) : e];                   \
        uint4 t = FTBL[(size_t)s0 * 16 + ch];                          \
        float wt = (rg < rem) ? 1.f : 0.f;                             \
        f32x2 w2 = {wt, wt};                                           \
        accA += w2 * (f32x2){bflo(t.x), bfhi(t.x)};                    \
        accB += w2 * (f32x2){bflo(t.y), bfhi(t.y)};                    \
        accC += w2 * (f32x2){bflo(t.z), bfhi(t.z)};                    \
        accD += w2 * (f32x2){bflo(t.w), bfhi(t.w)};                    \
    }                                                                  \
    float acc0 = accA[0], acc1 = accA[1];                              \
    float acc2 = accB[0], acc3 = accB[1];                              \
    float acc4 = accC[0], acc5 = accC[1];                              \
    float acc6 = accD[0], acc7 = accD[1];                              \
    acc0 += __shfl_xor(acc0, 32); acc1 += __shfl_xor(acc1, 32);        \
    acc2 += __shfl_xor(acc2, 32); acc3 += __shfl_xor(acc3, 32);        \
    acc4 += __shfl_xor(acc4, 32); acc5 += __shfl_xor(acc5, 32);        \
    acc6 += __shfl_xor(acc6, 32); acc7 += __shfl_xor(acc7, 32);        \
    acc0 += __shfl_xor(acc0, 16); acc1 += __shfl_xor(acc1, 16);        \
    acc2 += __shfl_xor(acc2, 16); acc3 += __shfl_xor(acc3, 16);        \
    acc4 += __shfl_xor(acc4, 16); acc5 += __shfl_xor(acc5, 16);        \
    acc6 += __shfl_xor(acc6, 16); acc7 += __shfl_xor(acc7, 16);

__global__ __launch_bounds__(256) void agg_mean_q(
    const unsigned short* __restrict__ featb, const int* __restrict__ csr_ptr,
    const float* __restrict__ deg_inv, const int* __restrict__ csr_src,
    unsigned short* __restrict__ outb) {
    int wid = threadIdx.x >> 6;
    int lane = threadIdx.x & 63;
    int v = blockIdx.x * 4 + wid;
    int start = csr_ptr[v], end = csr_ptr[v + 1];
    int rg = lane >> 4, ch = lane & 15;
    const uint4* f4 = (const uint4*)featb;  // 16 uint4 per 256B row
    f32x2 accA = {0.f, 0.f}, accB = {0.f, 0.f};
    f32x2 accC = {0.f, 0.f}, accD = {0.f, 0.f};
    AGG_BODY(f4);
    if (lane < 16) {
        float di = deg_inv[v];
        u16x8 o = {f2bf(acc0 * di), f2bf(acc1 * di), f2bf(acc2 * di), f2bf(acc3 * di),
                   f2bf(acc4 * di), f2bf(acc5 * di), f2bf(acc6 * di), f2bf(acc7 * di)};
        ((u16x8*)outb)[(size_t)v * 16 + ch] = o;
    }
}

__global__ __launch_bounds__(256) void agg_add_q(
    const unsigned short* __restrict__ zb, const int* __restrict__ csr_ptr,
    const float* __restrict__ deg_inv, const int* __restrict__ csr_src,
    float* __restrict__ out) {
    int wid = threadIdx.x >> 6;
    int lane = threadIdx.x & 63;
    int v = blockIdx.x * 4 + wid;
    int start = csr_ptr[v], end = csr_ptr[v + 1];
    int rg = lane >> 4, ch = lane & 15;
    const uint4* f4 = (const uint4*)zb;
    f32x2 accA = {0.f, 0.f}, accB = {0.f, 0.f};
    f32x2 accC = {0.f, 0.f}, accD = {0.f, 0.f};
    AGG_BODY(f4);
    if (lane < 16) {
        float di = deg_inv[v];
        f32x4* o4 = (f32x4*)out;  // 32 f32x4 per 512B row
        size_t base = (size_t)v * 32 + ch * 2;
        f32x4 c0 = __builtin_nontemporal_load(&o4[base]);
        f32x4 c1 = __builtin_nontemporal_load(&o4[base + 1]);
        c0[0] += acc0 * di; c0[1] += acc1 * di; c0[2] += acc2 * di; c0[3] += acc3 * di;
        c1[0] += acc4 * di; c1[1] += acc5 * di; c1[2] += acc6 * di; c1[3] += acc7 * di;
        __builtin_nontemporal_store(c0, &o4[base]);
        __builtin_nontemporal_store(c1, &o4[base + 1]);
    }
}

// ---------------- MFMA GEMMs (M=64 tiles, latency-optimized r10) ----------------

__global__ __launch_bounds__(256, 4) void gemm1_mfma(
    const unsigned short* __restrict__ xb, const unsigned short* __restrict__ aggb,
    const unsigned short* __restrict__ W1t, const float* __restrict__ b1p,
    unsigned short* __restrict__ h1b) {
    __shared__ __align__(16) unsigned short A_lds[64][40];
    __shared__ __align__(16) unsigned short B_lds[160][40];
    int tid = threadIdx.x;
    int m0 = blockIdx.x * 64;
    int w = tid >> 6, lane = tid & 63;
    int lrow = lane & 15, quad = lane >> 4;
    int wr = (w & 1) * 32;
    int wc = (w >> 1) * 80;
    f32x4 acc[2][5];
    #pragma unroll
    for (int r = 0; r < 2; r++)
        #pragma unroll
        for (int c = 0; c < 5; c++) acc[r][c] = (f32x4){0.f, 0.f, 0.f, 0.f};

    for (int k0 = 0; k0 < 256; k0 += 32) {
        __syncthreads();
        {
            int row = tid >> 2, ch = tid & 3;
            int gm = m0 + row, gk = k0 + ch * 8;
            u16x8 val = {0, 0, 0, 0, 0, 0, 0, 0};
            if (gm < NN) {
                const unsigned short* sp = (gk < 128)
                    ? (xb + (size_t)gm * 128 + gk)
                    : (aggb + (size_t)gm * 128 + (gk - 128));
                val = *(const u16x8*)sp;
            }
            *(u16x8*)&A_lds[row][ch * 8] = val;
        }
        #pragma unroll
        for (int i = 0; i < 3; i++) {
            int idx = tid + i * 256;
            if (idx < 640) {
                int n = idx >> 2, ch = idx & 3;
                u16x8 val = *(const u16x8*)(W1t + (size_t)n * 256 + k0 + ch * 8);
                *(u16x8*)&B_lds[n][ch * 8] = val;
            }
        }
        __syncthreads();
        bf16x8 a[2], b[5];
        #pragma unroll
        for (int r = 0; r < 2; r++)
            a[r] = *(const bf16x8*)&A_lds[wr + r * 16 + lrow][quad * 8];
        #pragma unroll
        for (int c = 0; c < 5; c++)
            b[c] = *(const bf16x8*)&B_lds[wc + c * 16 + lrow][quad * 8];
        #pragma unroll
        for (int r = 0; r < 2; r++)
            #pragma unroll
            for (int c = 0; c < 5; c++)
                acc[r][c] = __builtin_amdgcn_mfma_f32_16x16x32_bf16(a[r], b[c], acc[r][c], 0, 0, 0);
    }
    #pragma unroll
    for (int r = 0; r < 2; r++) {
        #pragma unroll
        for (int rr = 0; rr < 4; rr++) {
            int gm = m0 + wr + r * 16 + quad * 4 + rr;
            if (gm < NN) {
                #pragma unroll
                for (int c = 0; c < 5; c++) {
                    int gn = wc + c * 16 + lrow;
                    float val = acc[r][c][rr] + b1p[gn];
                    val = val > 0.f ? val : 0.f;
                    h1b[(size_t)gm * 160 + gn] = f2bf(val);
                }
            }
        }
    }
}

__global__ __launch_bounds__(256, 4) void gemm2_mfma(
    const unsigned short* __restrict__ h1b, const unsigned short* __restrict__ W2t,
    const float* __restrict__ b2, float* __restrict__ out,
    unsigned short* __restrict__ zb) {
    __shared__ __align__(16) unsigned short A_lds[64][40];
    __shared__ __align__(16) unsigned short B_lds[128][40];
    int tid = threadIdx.x;
    int m0 = blockIdx.x * 64;
    int n0 = blockIdx.y * 128;
    int w = tid >> 6, lane = tid & 63;
    int lrow = lane & 15, quad = lane >> 4;
    int wr = (w & 1) * 32;
    int wc = (w >> 1) * 64;
    f32x4 acc[2][4];
    #pragma unroll
    for (int r = 0; r < 2; r++)
        #pragma unroll
        for (int c = 0; c < 4; c++) acc[r][c] = (f32x4){0.f, 0.f, 0.f, 0.f};

    for (int k0 = 0; k0 < 160; k0 += 32) {
        __syncthreads();
        {
            int row = tid >> 2, ch = tid & 3;
            int gm = m0 + row;
            u16x8 val = {0, 0, 0, 0, 0, 0, 0, 0};
            if (gm < NN) val = *(const u16x8*)(h1b + (size_t)gm * 160 + k0 + ch * 8);
            *(u16x8*)&A_lds[row][ch * 8] = val;
        }
        #pragma unroll
        for (int i = 0; i < 2; i++) {
            int idx = tid + i * 256;
            int n = idx >> 2, ch = idx & 3;
            u16x8 val = *(const u16x8*)(W2t + (size_t)(n0 + n) * 160 + k0 + ch * 8);
            *(u16x8*)&B_lds[n][ch * 8] = val;
        }
        __syncthreads();
        bf16x8 a[2], b[4];
        #pragma unroll
        for (int r = 0; r < 2; r++)
            a[r] = *(const bf16x8*)&A_lds[wr + r * 16 + lrow][quad * 8];
        #pragma unroll
        for (int c = 0; c < 4; c++)
            b[c] = *(const bf16x8*)&B_lds[wc + c * 16 + lrow][quad * 8];
        #pragma unroll
        for (int r = 0; r < 2; r++)
            #pragma unroll
            for (int c = 0; c < 4; c++)
                acc[r][c] = __builtin_amdgcn_mfma_f32_16x16x32_bf16(a[r], b[c], acc[r][c], 0, 0, 0);
    }
    #pragma unroll
    for (int r = 0; r < 2; r++) {
        #pragma unroll
        for (int rr = 0; rr < 4; rr++) {
            int gm = m0 + wr + r * 16 + quad * 4 + rr;
            if (gm < NN) {
                #pragma unroll
                for (int c = 0; c < 4; c++) {
                    int gn = wc + c * 16 + lrow;
                    float val = acc[r][c][rr];
                    if (n0 == 0) {
                        out[(size_t)gm * 128 + gn] = val + b2[gn];
                    } else {
                        zb[(size_t)gm * 128 + gn] = f2bf(val);
                    }
                }
            }
        }
    }
}

// ---------------- launch ----------------

extern "C" void kernel_launch(void* const* d_in, const int* in_sizes, int n_in,
                              void* d_out, int out_size, void* d_ws, size_t ws_size,
                              hipStream_t stream) {
    const float* x   = (const float*)d_in[0];
    const int* src   = (const int*)d_in[1];
    const int* dst   = (const int*)d_in[2];
    const float* Ws1 = (const float*)d_in[3];
    const float* Wn1 = (const float*)d_in[4];
    const float* b1  = (const float*)d_in[5];
    const float* Ws2 = (const float*)d_in[6];
    const float* Wn2 = (const float*)d_in[7];
    const float* b2  = (const float*)d_in[8];
    float* out = (float*)d_out;

    char* p = (char*)d_ws;
    auto carve = [&](size_t bytes) {
        void* r = (void*)p;
        p += (bytes + 255) & ~(size_t)255;
        return r;
    };
    int*   csr_ptr  = (int*)carve((size_t)(NN + 1) * 4);
    float* deg_inv  = (float*)carve((size_t)NN * 4);
    int*   csr_src  = (int*)carve((size_t)NE * 4);
    int*   cntm     = (int*)carve((size_t)CNTL * 4);
    int*   offm     = (int*)carve((size_t)CNTL * 4);
    int*   segsta   = (int*)carve((size_t)CNTL * 4);
    int*   blk2     = (int*)carve(512 * 4);
    unsigned short* xb   = (unsigned short*)carve((size_t)NN * 128 * 2);
    unsigned short* aggb = (unsigned short*)carve((size_t)NN * 128 * 2);
    unsigned short* zb   = (unsigned short*)carve((size_t)NN * 128 * 2);
    unsigned short* W1t  = (unsigned short*)carve(160 * 256 * 2);
    unsigned short* W2t  = (unsigned short*)carve(256 * 160 * 2);
    float* b1p           = (float*)carve(160 * 4);
    unsigned short* h1b  = (unsigned short*)carve((size_t)NN * 160 * 2);
    // sort buffer aliases h1b's 32 MB region (dead until gemm1 runs)
    unsigned int* chunkw = (unsigned int*)h1b;                            // 6.4 MB

    // CSR build: radix sort by bucket (5 dispatches; sort3 merged into
    // buildcsr2 — LDS scatter never needed bucket-major ordering)
    sort1<<<WGS, 256, 0, stream>>>(src, dst, chunkw, cntm, segsta);
    const int SB = (CNTL + 255) / 256;  // 307
    scanA<<<SB, 256, 0, stream>>>(cntm, offm, blk2, CNTL);
    scanB<<<1, 512, 0, stream>>>(blk2, SB);
    scanC<<<SB, 256, 0, stream>>>(offm, blk2, CNTL);
    buildcsr2<<<NBK, 256, 0, stream>>>(chunkw, cntm, segsta, offm,
                                       csr_ptr, deg_inv, csr_src);

    // casts + weight packing
    cast_bf16<<<(NN * 128 / 8 + 255) / 256, 256, 0, stream>>>(x, xb, NN * 128 / 8);
    pack_weights<<<(160 * 256 + 256 * 160 + 160 + 255) / 256, 256, 0, stream>>>(
        Ws1, Wn1, b1, Ws2, Wn2, W1t, W2t, b1p);

    // layer 1
    agg_mean_q<<<NN / 4, 256, 0, stream>>>(xb, csr_ptr, deg_inv, csr_src, aggb);
    gemm1_mfma<<<dim3((NN + 63) / 64, 1), 256, 0, stream>>>(xb, aggb, W1t, b1p, h1b);

    // layer 2
    gemm2_mfma<<<dim3((NN + 63) / 64, 2), 256, 0, stream>>>(h1b, W2t, b2, out, zb);
    agg_add_q<<<NN / 4, 256, 0, stream>>>(zb, csr_ptr, deg_inv, csr_src, out);

    (void)in_sizes; (void)n_in; (void)out_size; (void)ws_size;
}